// Round 3
// baseline (6893.274 us; speedup 1.0000x reference)
//
#include <hip/hip_runtime.h>
#include <math.h>
#include <float.h>

#define BN_EPS 1e-5f

// Exact (non-contracted) squared distance, matching numpy's mul-then-add
// left-to-right association. Critical: FPS/KNN *selections* must match ref.
__device__ __forceinline__ float sqdist_exact(float dx, float dy, float dz) {
  return __fadd_rn(__fadd_rn(__fmul_rn(dx, dx), __fmul_rn(dy, dy)), __fmul_rn(dz, dz));
}

// ---------------- MLP1: h1 = x @ W1  (3 -> 32) ----------------
__global__ void __launch_bounds__(256) mlp1_kernel(const float* __restrict__ x,
                                                   const float* __restrict__ W1,
                                                   float* __restrict__ h1, int rows) {
  int tid = blockIdx.x * 256 + threadIdx.x;
  int row = tid >> 5;
  int d = tid & 31;
  if (row >= rows) return;
  float x0 = x[row * 3 + 0], x1 = x[row * 3 + 1], x2 = x[row * 3 + 2];
  float acc = x0 * W1[d] + x1 * W1[32 + d] + x2 * W1[64 + d];
  h1[row * 32 + d] = acc;
}

// ---------------- per-channel sum/sumsq over flat (n, D) ----------------
__global__ void stats_kernel(const float* __restrict__ v, int n, int D,
                             float* __restrict__ partial) {
  int tid = blockIdx.x * blockDim.x + threadIdx.x;
  int stride = blockDim.x * gridDim.x;
  float s = 0.f, q = 0.f;
  for (int i = tid; i < n; i += stride) { float a = v[i]; s += a; q += a * a; }
  int c = tid % D;
  extern __shared__ float sm[];  // 2*D
  for (int i = threadIdx.x; i < 2 * D; i += blockDim.x) sm[i] = 0.f;
  __syncthreads();
  atomicAdd(&sm[c], s);
  atomicAdd(&sm[D + c], q);
  __syncthreads();
  for (int i = threadIdx.x; i < 2 * D; i += blockDim.x)
    atomicAdd(&partial[(blockIdx.x & 63) * 2 * D + i], sm[i]);
}

// ---------------- finalize: partial sums -> scale/shift ----------------
__global__ void finalize_kernel(const float* __restrict__ partial,
                                const float* __restrict__ g, const float* __restrict__ b,
                                float cnt, int D, float* __restrict__ ss) {
  int d = threadIdx.x;
  if (d >= D) return;
  float s = 0.f, q = 0.f;
  for (int j = 0; j < 64; j++) { s += partial[j * 2 * D + d]; q += partial[j * 2 * D + D + d]; }
  float mean = s / cnt;
  float var = q / cnt - mean * mean;
  var = fmaxf(var, 0.f);
  float sc = g[d] * rsqrtf(var + BN_EPS);
  ss[d] = sc;
  ss[D + d] = b[d] - mean * sc;
}

// ---------------- apply BN+ReLU to pooled max/min (in-place on vmax) ----------------
__global__ void bn_apply_kernel(float* __restrict__ vmax, const float* __restrict__ vmin,
                                const float* __restrict__ ss, int D, int n) {
  int tid = blockIdx.x * blockDim.x + threadIdx.x;
  int stride = blockDim.x * gridDim.x;
  for (int i = tid; i < n; i += stride) {
    int d = i % D;
    float sc = ss[d], sh = ss[D + d];
    float v = (sc >= 0.f) ? vmax[i] : vmin[i];
    vmax[i] = fmaxf(v * sc + sh, 0.f);
  }
}

// ---------------- FPS v3: packed u64 keys + DPP wave reduce ----------------
// Key = (float_bits(dist) << 32) | ~index. dist >= 0 so IEEE order == uint
// order; max key == max dist with first-index tie-break (matches jnp.argmax).
// DPP row_shr 1/2/4/8 + row_bcast15/31: wave max lands in lane 63, VALU pipe
// only (no LDS-pipe shuffle latency).
#define DPP_STEP(CTRL)                                                                   \
  {                                                                                      \
    unsigned int nhi = (unsigned int)__builtin_amdgcn_update_dpp((int)khi, (int)khi,     \
                                                                 CTRL, 0xf, 0xf, false); \
    unsigned int nlo = (unsigned int)__builtin_amdgcn_update_dpp((int)klo, (int)klo,     \
                                                                 CTRL, 0xf, 0xf, false); \
    unsigned long long nk = (((unsigned long long)nhi) << 32) | nlo;                     \
    if (nk > wk) { wk = nk; khi = nhi; klo = nlo; }                                      \
  }

template <int P, int NW>
__global__ void __launch_bounds__(NW * 64) fps3_kernel(const float* __restrict__ p,
                                                       float* __restrict__ newp,
                                                       int N, int M) {
  constexpr int BS = NW * 64;
  const int b = blockIdx.x;
  const int t = threadIdx.x;
  const int wv = t >> 6;
  const float* pb = p + (size_t)b * N * 3;
  float px[P], py[P], pz[P], md[P];
#pragma unroll
  for (int j = 0; j < P; j++) {
    int i = j * BS + t;
    px[j] = pb[3 * i]; py[j] = pb[3 * i + 1]; pz[j] = pb[3 * i + 2];
    md[j] = INFINITY;
  }
  float lx = pb[0], ly = pb[1], lz = pb[2];
  if (t == 0) {
    newp[(size_t)b * M * 3 + 0] = lx;
    newp[(size_t)b * M * 3 + 1] = ly;
    newp[(size_t)b * M * 3 + 2] = lz;
  }
  __shared__ float slots[2 * NW * 8];

  for (int r = 1; r < M; r++) {
    // --- local scan + in-register pairwise tree (key carries coords along) ---
    unsigned long long tk[P];
    float tx[P], ty[P], tz[P];
#pragma unroll
    for (int j = 0; j < P; j++) {
      float d = sqdist_exact(px[j] - lx, py[j] - ly, pz[j] - lz);
      float m = fminf(md[j], d);
      md[j] = m;
      tk[j] = (((unsigned long long)__float_as_uint(m)) << 32) |
              (unsigned int)(~(j * BS + t));
      tx[j] = px[j]; ty[j] = py[j]; tz[j] = pz[j];
    }
#pragma unroll
    for (int w = P / 2; w >= 1; w >>= 1)
#pragma unroll
      for (int j = 0; j < w; j++)
        if (tk[j + w] > tk[j]) {
          tk[j] = tk[j + w]; tx[j] = tx[j + w]; ty[j] = ty[j + w]; tz[j] = tz[j + w];
        }
    const unsigned long long bk = tk[0];
    const float bx = tx[0], by = ty[0], bz = tz[0];

    // --- wave reduce via DPP (result in lane 63) ---
    unsigned int khi = (unsigned int)(bk >> 32);
    unsigned int klo = (unsigned int)bk;
    unsigned long long wk = bk;
    DPP_STEP(0x111);  // row_shr:1
    DPP_STEP(0x112);  // row_shr:2
    DPP_STEP(0x114);  // row_shr:4
    DPP_STEP(0x118);  // row_shr:8
    DPP_STEP(0x142);  // row_bcast:15
    DPP_STEP(0x143);  // row_bcast:31
    unsigned int whi = (unsigned int)__builtin_amdgcn_readlane((int)(wk >> 32), 63);
    unsigned int wlo = (unsigned int)__builtin_amdgcn_readlane((int)wk, 63);
    unsigned long long wavek = (((unsigned long long)whi) << 32) | wlo;

    if constexpr (NW == 1) {
      int idx = (int)(~wlo);
      int owner = idx & 63;
      lx = __uint_as_float((unsigned int)__builtin_amdgcn_readlane((int)__float_as_uint(bx), owner));
      ly = __uint_as_float((unsigned int)__builtin_amdgcn_readlane((int)__float_as_uint(by), owner));
      lz = __uint_as_float((unsigned int)__builtin_amdgcn_readlane((int)__float_as_uint(bz), owner));
      if (t == 0) {
        size_t o = ((size_t)b * M + r) * 3;
        newp[o] = lx; newp[o + 1] = ly; newp[o + 2] = lz;
      }
    } else {
      float* base = slots + (r & 1) * NW * 8;
      if (bk == wavek) {  // unique owner lane of this wave
        float* slot = base + wv * 8;
        slot[0] = __uint_as_float(whi);
        slot[1] = __uint_as_float(wlo);
        slot[2] = bx; slot[3] = by; slot[4] = bz;
      }
      __syncthreads();
      unsigned long long fk = 0;
      float fx = 0.f, fy = 0.f, fz = 0.f;
#pragma unroll
      for (int w = 0; w < NW; w++) {
        const float4 s4 = *reinterpret_cast<const float4*>(base + w * 8);
        float sz = base[w * 8 + 4];
        unsigned long long k2 = (((unsigned long long)__float_as_uint(s4.x)) << 32) |
                                __float_as_uint(s4.y);
        if (k2 > fk) { fk = k2; fx = s4.z; fy = s4.w; fz = sz; }
      }
      lx = fx; ly = fy; lz = fz;
      if (t == 0) {
        size_t o = ((size_t)b * M + r) * 3;
        newp[o] = fx; newp[o + 1] = fy; newp[o + 2] = fz;
      }
    }
  }
}

// ---------------- KNN: one wave per query, top-16 smallest distances ----------------
__global__ void __launch_bounds__(256) knn_kernel(const float* __restrict__ p,
                                                  const float* __restrict__ newp,
                                                  int N, int M, int BM,
                                                  int* __restrict__ nidx) {
  int gwid = (blockIdx.x * 256 + threadIdx.x) >> 6;
  int lane = threadIdx.x & 63;
  if (gwid >= BM) return;
  int b = gwid / M;
  const float* pb = p + (size_t)b * N * 3;
  float qx = newp[(size_t)gwid * 3], qy = newp[(size_t)gwid * 3 + 1], qz = newp[(size_t)gwid * 3 + 2];
  float bd[16];
  int bi[16];
#pragma unroll
  for (int s = 0; s < 16; s++) { bd[s] = INFINITY; bi[s] = 0x7FFFFFFF; }
  for (int c = lane; c < N; c += 64) {
    float d = sqdist_exact(pb[3 * c] - qx, pb[3 * c + 1] - qy, pb[3 * c + 2] - qz);
    if (d < bd[15]) {
      bd[15] = d; bi[15] = c;
#pragma unroll
      for (int s = 15; s >= 1; --s) {
        bool sw = bd[s] < bd[s - 1];
        if (sw) {
          float tf = bd[s]; bd[s] = bd[s - 1]; bd[s - 1] = tf;
          int ti = bi[s]; bi[s] = bi[s - 1]; bi[s - 1] = ti;
        }
      }
    }
  }
  int out = 0;
  for (int r = 0; r < 16; r++) {
    float v = bd[0]; int ii = bi[0];
    float mv = v; int mi = ii;
#pragma unroll
    for (int m = 1; m < 64; m <<= 1) {
      float v2 = __shfl_xor(mv, m);
      int i2 = __shfl_xor(mi, m);
      if (v2 < mv || (v2 == mv && i2 < mi)) { mv = v2; mi = i2; }
    }
    if (mi == ii) {
#pragma unroll
      for (int s = 0; s < 15; s++) { bd[s] = bd[s + 1]; bi[s] = bi[s + 1]; }
      bd[15] = INFINITY; bi[15] = 0x7FFFFFFF;
    }
    if (lane == r) out = mi;
  }
  if (lane < 16) nidx[(size_t)gwid * 16 + lane] = out;
}

// ---------------- gather + GEMM + stats + max/min pool over k=16 ----------------
__global__ void __launch_bounds__(256) gemm_kernel(
    const float* __restrict__ p, const float* __restrict__ h, const float* __restrict__ newp,
    const int* __restrict__ nidx, const float* __restrict__ W,
    float* __restrict__ ymax, float* __restrict__ ymin, float* __restrict__ partial,
    int N, int M, int BM, int Ch, int Cpad, int D, int Gseq) {
  extern __shared__ float sm[];
  int Ctot = Ch + 3;
  int TD = D < 256 ? D : 256;
  int Gpar = 256 / TD;
  float* sfeat = sm;                      // Gpar*16*Cpad
  float* sstat = sm + Gpar * 16 * Cpad;   // 2*D
  int t = threadIdx.x;
  for (int i = t; i < 2 * D; i += 256) sstat[i] = 0.f;
  int mloc = t / TD;
  int dbase = t % TD;
  int DV = D / TD;  // 1 or 2
  __syncthreads();
  for (int s = 0; s < Gseq; s++) {
    int grp0 = (blockIdx.x * Gseq + s) * Gpar;
    if (grp0 >= BM) break;
    int nf = Gpar * 16 * Cpad;
    for (int i = t; i < nf; i += 256) {
      int c = i % Cpad;
      int rk = i / Cpad;
      int k = rk & 15;
      int g = rk >> 4;
      int grp = grp0 + g;
      float val = 0.f;
      if (grp < BM && c < Ctot) {
        int b = grp / M;
        int nb = nidx[(size_t)grp * 16 + k];
        if (c < 3)
          val = p[((size_t)b * N + nb) * 3 + c] - newp[(size_t)grp * 3 + c];
        else
          val = h[((size_t)b * N + nb) * Ch + (c - 3)];
      }
      sfeat[i] = val;
    }
    __syncthreads();
    int grp = grp0 + mloc;
    bool act = grp < BM;
    const float* fr = sfeat + mloc * 16 * Cpad;
    for (int dv = 0; dv < DV; ++dv) {
      int d = dbase + (dv << 8);
      float acc[16];
#pragma unroll
      for (int k = 0; k < 16; k++) acc[k] = 0.f;
      for (int c = 0; c < Cpad; c += 4) {
        float w0 = (c < Ctot) ? W[(size_t)c * D + d] : 0.f;
        float w1 = (c + 1 < Ctot) ? W[(size_t)(c + 1) * D + d] : 0.f;
        float w2 = (c + 2 < Ctot) ? W[(size_t)(c + 2) * D + d] : 0.f;
        float w3 = (c + 3 < Ctot) ? W[(size_t)(c + 3) * D + d] : 0.f;
#pragma unroll
        for (int k = 0; k < 16; k++) {
          const float4 f = *reinterpret_cast<const float4*>(fr + k * Cpad + c);
          acc[k] += f.x * w0 + f.y * w1 + f.z * w2 + f.w * w3;
        }
      }
      if (act) {
        float ssum = 0.f, ssq = 0.f, amax = -INFINITY, amin = INFINITY;
#pragma unroll
        for (int k = 0; k < 16; k++) {
          float a = acc[k];
          ssum += a; ssq += a * a;
          amax = fmaxf(amax, a); amin = fminf(amin, a);
        }
        ymax[(size_t)grp * D + d] = amax;
        ymin[(size_t)grp * D + d] = amin;
        atomicAdd(&sstat[d], ssum);
        atomicAdd(&sstat[D + d], ssq);
      }
    }
    __syncthreads();
  }
  for (int i = t; i < 2 * D; i += 256)
    atomicAdd(&partial[(blockIdx.x & 63) * 2 * D + i], sstat[i]);
}

// ---------------- classifier head: mean-pool + 3 layers, single block ----------------
__global__ void __launch_bounds__(512) classifier_kernel(
    const float* __restrict__ h4,
    const float* __restrict__ Wc1, const float* __restrict__ bc1,
    const float* __restrict__ gc1, const float* __restrict__ hc1,
    const float* __restrict__ Wc2, const float* __restrict__ bc2,
    const float* __restrict__ gc2, const float* __restrict__ hc2,
    const float* __restrict__ Wc3, const float* __restrict__ bc3,
    float* __restrict__ out) {
  __shared__ float z[16 * 512];
  __shared__ float z1[16 * 256];
  __shared__ float z2[16 * 128];
  __shared__ float sc[256], sh[256];
  int t = threadIdx.x;
  for (int i = t; i < 16 * 512; i += 512) {
    int b = i >> 9, c = i & 511;
    float s = 0.f;
    for (int k = 0; k < 16; k++) s += h4[((size_t)b * 16 + k) * 512 + c];
    z[i] = s * (1.f / 16.f);
  }
  __syncthreads();
  for (int i = t; i < 16 * 256; i += 512) {
    int b = i >> 8, d = i & 255;
    float a = bc1[d];
    for (int c = 0; c < 512; c++) a += z[(b << 9) + c] * Wc1[c * 256 + d];
    z1[i] = a;
  }
  __syncthreads();
  if (t < 256) {
    float s = 0.f, q = 0.f;
    for (int b = 0; b < 16; b++) { float a = z1[(b << 8) + t]; s += a; q += a * a; }
    float mean = s * (1.f / 16.f);
    float var = fmaxf(q * (1.f / 16.f) - mean * mean, 0.f);
    float scl = gc1[t] * rsqrtf(var + BN_EPS);
    sc[t] = scl; sh[t] = hc1[t] - mean * scl;
  }
  __syncthreads();
  for (int i = t; i < 16 * 256; i += 512) {
    int d = i & 255;
    z1[i] = fmaxf(z1[i] * sc[d] + sh[d], 0.f);
  }
  __syncthreads();
  for (int i = t; i < 16 * 128; i += 512) {
    int b = i >> 7, d = i & 127;
    float a = bc2[d];
    for (int c = 0; c < 256; c++) a += z1[(b << 8) + c] * Wc2[c * 128 + d];
    z2[i] = a;
  }
  __syncthreads();
  if (t < 128) {
    float s = 0.f, q = 0.f;
    for (int b = 0; b < 16; b++) { float a = z2[(b << 7) + t]; s += a; q += a * a; }
    float mean = s * (1.f / 16.f);
    float var = fmaxf(q * (1.f / 16.f) - mean * mean, 0.f);
    float scl = gc2[t] * rsqrtf(var + BN_EPS);
    sc[t] = scl; sh[t] = hc2[t] - mean * scl;
  }
  __syncthreads();
  for (int i = t; i < 16 * 128; i += 512) {
    int d = i & 127;
    z2[i] = fmaxf(z2[i] * sc[d] + sh[d], 0.f);
  }
  __syncthreads();
  for (int i = t; i < 640; i += 512) {
    int b = i / 40, d = i % 40;
    float a = bc3[d];
    for (int c = 0; c < 128; c++) a += z2[(b << 7) + c] * Wc3[c * 40 + d];
    out[i] = a;
  }
}

extern "C" void kernel_launch(void* const* d_in, const int* in_sizes, int n_in,
                              void* d_out, int out_size, void* d_ws, size_t ws_size,
                              hipStream_t stream) {
  (void)in_sizes; (void)n_in; (void)out_size; (void)ws_size;
  const float* x   = (const float*)d_in[0];
  const float* W1  = (const float*)d_in[1];
  const float* g1  = (const float*)d_in[2];
  const float* b1  = (const float*)d_in[3];
  const float* W2  = (const float*)d_in[4];
  const float* g2  = (const float*)d_in[5];
  const float* b2  = (const float*)d_in[6];
  const float* W3  = (const float*)d_in[7];
  const float* g3  = (const float*)d_in[8];
  const float* b3  = (const float*)d_in[9];
  const float* W4  = (const float*)d_in[10];
  const float* g4  = (const float*)d_in[11];
  const float* b4  = (const float*)d_in[12];
  const float* W5  = (const float*)d_in[13];
  const float* g5  = (const float*)d_in[14];
  const float* b5  = (const float*)d_in[15];
  const float* Wc1 = (const float*)d_in[16];
  const float* bc1 = (const float*)d_in[17];
  const float* gc1 = (const float*)d_in[18];
  const float* hc1 = (const float*)d_in[19];
  const float* Wc2 = (const float*)d_in[20];
  const float* bc2 = (const float*)d_in[21];
  const float* gc2 = (const float*)d_in[22];
  const float* hc2 = (const float*)d_in[23];
  const float* Wc3 = (const float*)d_in[24];
  const float* bc3 = (const float*)d_in[25];
  float* out = (float*)d_out;

  float* ws = (float*)d_ws;
  float* HA   = ws;                  // 2,097,152 (h1; stage2 out; stage4 out)
  float* HB   = HA + 2097152;        // 1,048,576 (stage1 out; stage3 out)
  float* YMIN = HB + 1048576;        // 1,048,576
  float* NP1  = YMIN + 1048576;      // 49,152
  float* NP2  = NP1 + 49152;         // 12,288
  float* NP3  = NP2 + 12288;         // 3,072
  float* NP4  = NP3 + 3072;          // 768
  int*   NIDX = (int*)(NP4 + 768);   // 262,144 ints
  float* PART = (float*)(NIDX + 262144);  // 5 * 65,536
  float* SS   = PART + 5 * 65536;         // 5 * 1,024

  hipMemsetAsync(PART, 0, 5 * 65536 * sizeof(float), stream);

  // --- MLP1 + BN(axes 0,1) + ReLU ---
  mlp1_kernel<<<(65536 * 32) / 256, 256, 0, stream>>>(x, W1, HA, 65536);
  stats_kernel<<<256, 256, 2 * 32 * sizeof(float), stream>>>(HA, 65536 * 32, 32, PART);
  finalize_kernel<<<1, 32, 0, stream>>>(PART, g1, b1, 65536.f, 32, SS);
  bn_apply_kernel<<<512, 256, 0, stream>>>(HA, HA, SS, 32, 65536 * 32);

  // --- stage 1: N=4096 -> M=1024, Ch=32 -> D=64 ---
  fps3_kernel<16, 4><<<16, 256, 0, stream>>>(x, NP1, 4096, 1024);
  knn_kernel<<<(16384 + 3) / 4, 256, 0, stream>>>(x, NP1, 4096, 1024, 16384, NIDX);
  gemm_kernel<<<512, 256, (4 * 16 * 36 + 2 * 64) * sizeof(float), stream>>>(
      x, HA, NP1, NIDX, W2, HB, YMIN, PART + 65536, 4096, 1024, 16384, 32, 36, 64, 8);
  finalize_kernel<<<1, 64, 0, stream>>>(PART + 65536, g2, b2, (float)(16384 * 16), 64, SS + 1024);
  bn_apply_kernel<<<512, 256, 0, stream>>>(HB, YMIN, SS + 1024, 64, 16384 * 64);

  // --- stage 2: N=1024 -> M=256, Ch=64 -> D=128 ---
  fps3_kernel<16, 1><<<16, 64, 0, stream>>>(NP1, NP2, 1024, 256);
  knn_kernel<<<(4096 + 3) / 4, 256, 0, stream>>>(NP1, NP2, 1024, 256, 4096, NIDX);
  gemm_kernel<<<512, 256, (2 * 16 * 68 + 2 * 128) * sizeof(float), stream>>>(
      NP1, HB, NP2, NIDX, W3, HA, YMIN, PART + 2 * 65536, 1024, 256, 4096, 64, 68, 128, 4);
  finalize_kernel<<<1, 128, 0, stream>>>(PART + 2 * 65536, g3, b3, (float)(4096 * 16), 128, SS + 2048);
  bn_apply_kernel<<<512, 256, 0, stream>>>(HA, YMIN, SS + 2048, 128, 4096 * 128);

  // --- stage 3: N=256 -> M=64, Ch=128 -> D=256 ---
  fps3_kernel<4, 1><<<16, 64, 0, stream>>>(NP2, NP3, 256, 64);
  knn_kernel<<<(1024 + 3) / 4, 256, 0, stream>>>(NP2, NP3, 256, 64, 1024, NIDX);
  gemm_kernel<<<512, 256, (16 * 132 + 2 * 256) * sizeof(float), stream>>>(
      NP2, HA, NP3, NIDX, W4, HB, YMIN, PART + 3 * 65536, 256, 64, 1024, 128, 132, 256, 2);
  finalize_kernel<<<1, 256, 0, stream>>>(PART + 3 * 65536, g4, b4, (float)(1024 * 16), 256, SS + 3072);
  bn_apply_kernel<<<512, 256, 0, stream>>>(HB, YMIN, SS + 3072, 256, 1024 * 256);

  // --- stage 4: N=64 -> M=16, Ch=256 -> D=512 ---
  fps3_kernel<1, 1><<<16, 64, 0, stream>>>(NP3, NP4, 64, 16);
  knn_kernel<<<(256 + 3) / 4, 256, 0, stream>>>(NP3, NP4, 64, 16, 256, NIDX);
  gemm_kernel<<<256, 256, (16 * 260 + 2 * 512) * sizeof(float), stream>>>(
      NP3, HB, NP4, NIDX, W5, HA, YMIN, PART + 4 * 65536, 64, 16, 256, 256, 260, 512, 1);
  finalize_kernel<<<1, 512, 0, stream>>>(PART + 4 * 65536, g5, b5, (float)(256 * 16), 512, SS + 4096);
  bn_apply_kernel<<<512, 256, 0, stream>>>(HA, YMIN, SS + 4096, 512, 256 * 512);

  // --- classifier head ---
  classifier_kernel<<<1, 512, 0, stream>>>(HA, Wc1, bc1, gc1, hc1, Wc2, bc2, gc2, hc2, Wc3, bc3, out);
}

// Round 4
// 1614.145 us; speedup vs baseline: 4.2705x; 4.2705x over previous
//
#include <hip/hip_runtime.h>
#include <math.h>
#include <float.h>

#define BN_EPS 1e-5f

// Exact (non-contracted) squared distance, matching numpy's mul-then-add
// left-to-right association. Critical: FPS/KNN *selections* must match ref.
__device__ __forceinline__ float sqdist_exact(float dx, float dy, float dz) {
  return __fadd_rn(__fadd_rn(__fmul_rn(dx, dx), __fmul_rn(dy, dy)), __fmul_rn(dz, dz));
}

// ---------------- MLP1: h1 = x @ W1  (3 -> 32) ----------------
__global__ void __launch_bounds__(256) mlp1_kernel(const float* __restrict__ x,
                                                   const float* __restrict__ W1,
                                                   float* __restrict__ h1, int rows) {
  int tid = blockIdx.x * 256 + threadIdx.x;
  int row = tid >> 5;
  int d = tid & 31;
  if (row >= rows) return;
  float x0 = x[row * 3 + 0], x1 = x[row * 3 + 1], x2 = x[row * 3 + 2];
  float acc = x0 * W1[d] + x1 * W1[32 + d] + x2 * W1[64 + d];
  h1[row * 32 + d] = acc;
}

// ---------------- per-channel sum/sumsq over flat (n, D) ----------------
__global__ void stats_kernel(const float* __restrict__ v, int n, int D,
                             float* __restrict__ partial) {
  int tid = blockIdx.x * blockDim.x + threadIdx.x;
  int stride = blockDim.x * gridDim.x;
  float s = 0.f, q = 0.f;
  for (int i = tid; i < n; i += stride) { float a = v[i]; s += a; q += a * a; }
  int c = tid % D;
  extern __shared__ float sm[];  // 2*D
  for (int i = threadIdx.x; i < 2 * D; i += blockDim.x) sm[i] = 0.f;
  __syncthreads();
  atomicAdd(&sm[c], s);
  atomicAdd(&sm[D + c], q);
  __syncthreads();
  for (int i = threadIdx.x; i < 2 * D; i += blockDim.x)
    atomicAdd(&partial[(blockIdx.x & 63) * 2 * D + i], sm[i]);
}

// ---------------- finalize: partial sums -> scale/shift ----------------
__global__ void finalize_kernel(const float* __restrict__ partial,
                                const float* __restrict__ g, const float* __restrict__ b,
                                float cnt, int D, float* __restrict__ ss) {
  int d = threadIdx.x;
  if (d >= D) return;
  float s = 0.f, q = 0.f;
  for (int j = 0; j < 64; j++) { s += partial[j * 2 * D + d]; q += partial[j * 2 * D + D + d]; }
  float mean = s / cnt;
  float var = q / cnt - mean * mean;
  var = fmaxf(var, 0.f);
  float sc = g[d] * rsqrtf(var + BN_EPS);
  ss[d] = sc;
  ss[D + d] = b[d] - mean * sc;
}

// ---------------- apply BN+ReLU to pooled max/min (in-place on vmax) ----------------
__global__ void bn_apply_kernel(float* __restrict__ vmax, const float* __restrict__ vmin,
                                const float* __restrict__ ss, int D, int n) {
  int tid = blockIdx.x * blockDim.x + threadIdx.x;
  int stride = blockDim.x * gridDim.x;
  for (int i = tid; i < n; i += stride) {
    int d = i % D;
    float sc = ss[d], sh = ss[D + d];
    float v = (sc >= 0.f) ? vmax[i] : vmin[i];
    vmax[i] = fmaxf(v * sc + sh, 0.f);
  }
}

// ---------------- FPS v4: DPP u64-key reduce, lean registers ----------------
// Key = (float_bits(dist) << 32) | ~index  (dist>=0 => IEEE order == uint
// order; max key == max dist, first-index tie-break, matches jnp.argmax).
// Scan carries only (bv,bi). Winner coords fetched from LDS-staged points
// (uniform broadcast read). NW>1: no global stores in the loop (selected
// points buffered in LDS, copied out at the end) so the per-round barrier
// waits on lgkmcnt only, never a vmcnt HBM drain.
#define DPP_STEP(CTRL)                                                                   \
  {                                                                                      \
    unsigned int nhi = (unsigned int)__builtin_amdgcn_update_dpp((int)khi, (int)khi,     \
                                                                 CTRL, 0xf, 0xf, false); \
    unsigned int nlo = (unsigned int)__builtin_amdgcn_update_dpp((int)klo, (int)klo,     \
                                                                 CTRL, 0xf, 0xf, false); \
    unsigned long long nk = (((unsigned long long)nhi) << 32) | nlo;                     \
    if (nk > wk) { wk = nk; khi = nhi; klo = nlo; }                                      \
  }

template <int P, int NW>
__global__ void __launch_bounds__(NW * 64) fps4_kernel(const float* __restrict__ p,
                                                       float* __restrict__ newp) {
  constexpr int BS = NW * 64;
  constexpr int N = P * BS;
  constexpr int M = N / 4;
  __shared__ float spts[N * 3];
  __shared__ float snew[NW > 1 ? M * 3 : 1];
  __shared__ unsigned long long slots[NW > 1 ? 2 * NW : 2];
  const int b = blockIdx.x;
  const int t = threadIdx.x;
  const int wv = t >> 6;
  const int lane = t & 63;
  const float* pb = p + (size_t)b * N * 3;
  float px[P], py[P], pz[P], md[P];
#pragma unroll
  for (int j = 0; j < P; j++) {
    int i = j * BS + t;
    float x = pb[3 * i], y = pb[3 * i + 1], z = pb[3 * i + 2];
    px[j] = x; py[j] = y; pz[j] = z; md[j] = INFINITY;
    spts[3 * i] = x; spts[3 * i + 1] = y; spts[3 * i + 2] = z;
  }
  float lx = pb[0], ly = pb[1], lz = pb[2];
  if (t == 0) {
    if constexpr (NW > 1) {
      snew[0] = lx; snew[1] = ly; snew[2] = lz;
    } else {
      newp[(size_t)b * M * 3 + 0] = lx;
      newp[(size_t)b * M * 3 + 1] = ly;
      newp[(size_t)b * M * 3 + 2] = lz;
    }
  }

  for (int r = 1; r < M; r++) {
    // serial scan: track (max min-dist, min index) only
    float bv; int bi;
    {
      float d0 = sqdist_exact(px[0] - lx, py[0] - ly, pz[0] - lz);
      float m0 = fminf(md[0], d0);
      md[0] = m0;
      bv = m0; bi = t;
    }
#pragma unroll
    for (int j = 1; j < P; j++) {
      float d = sqdist_exact(px[j] - lx, py[j] - ly, pz[j] - lz);
      float m = fminf(md[j], d);
      md[j] = m;
      if (m > bv) { bv = m; bi = j * BS + t; }  // strict >: first-index ties
    }
    unsigned int khi = __float_as_uint(bv);
    unsigned int klo = ~(unsigned int)bi;
    unsigned long long wk = (((unsigned long long)khi) << 32) | klo;
    DPP_STEP(0x111);  // row_shr:1
    DPP_STEP(0x112);  // row_shr:2
    DPP_STEP(0x114);  // row_shr:4
    DPP_STEP(0x118);  // row_shr:8
    DPP_STEP(0x142);  // row_bcast:15
    DPP_STEP(0x143);  // row_bcast:31
    // wave max now in lane 63's wk
    unsigned int gidx;
    if constexpr (NW == 1) {
      unsigned int wlo = (unsigned int)__builtin_amdgcn_readlane((int)wk, 63);
      gidx = ~wlo;
    } else {
      unsigned long long* base = slots + (r & 1) * NW;
      if (lane == 63) base[wv] = wk;
      __syncthreads();
      unsigned long long fk = base[0];
#pragma unroll
      for (int w = 1; w < NW; w++) {
        unsigned long long k2 = base[w];
        if (k2 > fk) fk = k2;
      }
      gidx = ~(unsigned int)fk;
    }
    // uniform LDS broadcast read of winner coords
    lx = spts[3 * gidx];
    ly = spts[3 * gidx + 1];
    lz = spts[3 * gidx + 2];
    if (t == 0) {
      if constexpr (NW > 1) {
        snew[3 * r] = lx; snew[3 * r + 1] = ly; snew[3 * r + 2] = lz;
      } else {
        size_t o = ((size_t)b * M + r) * 3;
        newp[o] = lx; newp[o + 1] = ly; newp[o + 2] = lz;
      }
    }
  }
  if constexpr (NW > 1) {
    __syncthreads();
    for (int i = t; i < M * 3; i += BS) newp[(size_t)b * M * 3 + i] = snew[i];
  }
}

// ---------------- KNN: one wave per query, top-16 smallest distances ----------------
__global__ void __launch_bounds__(256) knn_kernel(const float* __restrict__ p,
                                                  const float* __restrict__ newp,
                                                  int N, int M, int BM,
                                                  int* __restrict__ nidx) {
  int gwid = (blockIdx.x * 256 + threadIdx.x) >> 6;
  int lane = threadIdx.x & 63;
  if (gwid >= BM) return;
  int b = gwid / M;
  const float* pb = p + (size_t)b * N * 3;
  float qx = newp[(size_t)gwid * 3], qy = newp[(size_t)gwid * 3 + 1], qz = newp[(size_t)gwid * 3 + 2];
  float bd[16];
  int bi[16];
#pragma unroll
  for (int s = 0; s < 16; s++) { bd[s] = INFINITY; bi[s] = 0x7FFFFFFF; }
  for (int c = lane; c < N; c += 64) {
    float d = sqdist_exact(pb[3 * c] - qx, pb[3 * c + 1] - qy, pb[3 * c + 2] - qz);
    if (d < bd[15]) {
      bd[15] = d; bi[15] = c;
#pragma unroll
      for (int s = 15; s >= 1; --s) {
        bool sw = bd[s] < bd[s - 1];
        if (sw) {
          float tf = bd[s]; bd[s] = bd[s - 1]; bd[s - 1] = tf;
          int ti = bi[s]; bi[s] = bi[s - 1]; bi[s - 1] = ti;
        }
      }
    }
  }
  int out = 0;
  for (int r = 0; r < 16; r++) {
    float v = bd[0]; int ii = bi[0];
    float mv = v; int mi = ii;
#pragma unroll
    for (int m = 1; m < 64; m <<= 1) {
      float v2 = __shfl_xor(mv, m);
      int i2 = __shfl_xor(mi, m);
      if (v2 < mv || (v2 == mv && i2 < mi)) { mv = v2; mi = i2; }
    }
    if (mi == ii) {
#pragma unroll
      for (int s = 0; s < 15; s++) { bd[s] = bd[s + 1]; bi[s] = bi[s + 1]; }
      bd[15] = INFINITY; bi[15] = 0x7FFFFFFF;
    }
    if (lane == r) out = mi;
  }
  if (lane < 16) nidx[(size_t)gwid * 16 + lane] = out;
}

// ---------------- gather + GEMM + stats + max/min pool over k=16 ----------------
__global__ void __launch_bounds__(256) gemm_kernel(
    const float* __restrict__ p, const float* __restrict__ h, const float* __restrict__ newp,
    const int* __restrict__ nidx, const float* __restrict__ W,
    float* __restrict__ ymax, float* __restrict__ ymin, float* __restrict__ partial,
    int N, int M, int BM, int Ch, int Cpad, int D, int Gseq) {
  extern __shared__ float sm[];
  int Ctot = Ch + 3;
  int TD = D < 256 ? D : 256;
  int Gpar = 256 / TD;
  float* sfeat = sm;                      // Gpar*16*Cpad
  float* sstat = sm + Gpar * 16 * Cpad;   // 2*D
  int t = threadIdx.x;
  for (int i = t; i < 2 * D; i += 256) sstat[i] = 0.f;
  int mloc = t / TD;
  int dbase = t % TD;
  int DV = D / TD;  // 1 or 2
  __syncthreads();
  for (int s = 0; s < Gseq; s++) {
    int grp0 = (blockIdx.x * Gseq + s) * Gpar;
    if (grp0 >= BM) break;
    int nf = Gpar * 16 * Cpad;
    for (int i = t; i < nf; i += 256) {
      int c = i % Cpad;
      int rk = i / Cpad;
      int k = rk & 15;
      int g = rk >> 4;
      int grp = grp0 + g;
      float val = 0.f;
      if (grp < BM && c < Ctot) {
        int b = grp / M;
        int nb = nidx[(size_t)grp * 16 + k];
        if (c < 3)
          val = p[((size_t)b * N + nb) * 3 + c] - newp[(size_t)grp * 3 + c];
        else
          val = h[((size_t)b * N + nb) * Ch + (c - 3)];
      }
      sfeat[i] = val;
    }
    __syncthreads();
    int grp = grp0 + mloc;
    bool act = grp < BM;
    const float* fr = sfeat + mloc * 16 * Cpad;
    for (int dv = 0; dv < DV; ++dv) {
      int d = dbase + (dv << 8);
      float acc[16];
#pragma unroll
      for (int k = 0; k < 16; k++) acc[k] = 0.f;
      for (int c = 0; c < Cpad; c += 4) {
        float w0 = (c < Ctot) ? W[(size_t)c * D + d] : 0.f;
        float w1 = (c + 1 < Ctot) ? W[(size_t)(c + 1) * D + d] : 0.f;
        float w2 = (c + 2 < Ctot) ? W[(size_t)(c + 2) * D + d] : 0.f;
        float w3 = (c + 3 < Ctot) ? W[(size_t)(c + 3) * D + d] : 0.f;
#pragma unroll
        for (int k = 0; k < 16; k++) {
          const float4 f = *reinterpret_cast<const float4*>(fr + k * Cpad + c);
          acc[k] += f.x * w0 + f.y * w1 + f.z * w2 + f.w * w3;
        }
      }
      if (act) {
        float ssum = 0.f, ssq = 0.f, amax = -INFINITY, amin = INFINITY;
#pragma unroll
        for (int k = 0; k < 16; k++) {
          float a = acc[k];
          ssum += a; ssq += a * a;
          amax = fmaxf(amax, a); amin = fminf(amin, a);
        }
        ymax[(size_t)grp * D + d] = amax;
        ymin[(size_t)grp * D + d] = amin;
        atomicAdd(&sstat[d], ssum);
        atomicAdd(&sstat[D + d], ssq);
      }
    }
    __syncthreads();
  }
  for (int i = t; i < 2 * D; i += 256)
    atomicAdd(&partial[(blockIdx.x & 63) * 2 * D + i], sstat[i]);
}

// ---------------- classifier head: mean-pool + 3 layers, single block ----------------
__global__ void __launch_bounds__(512) classifier_kernel(
    const float* __restrict__ h4,
    const float* __restrict__ Wc1, const float* __restrict__ bc1,
    const float* __restrict__ gc1, const float* __restrict__ hc1,
    const float* __restrict__ Wc2, const float* __restrict__ bc2,
    const float* __restrict__ gc2, const float* __restrict__ hc2,
    const float* __restrict__ Wc3, const float* __restrict__ bc3,
    float* __restrict__ out) {
  __shared__ float z[16 * 512];
  __shared__ float z1[16 * 256];
  __shared__ float z2[16 * 128];
  __shared__ float sc[256], sh[256];
  int t = threadIdx.x;
  for (int i = t; i < 16 * 512; i += 512) {
    int b = i >> 9, c = i & 511;
    float s = 0.f;
    for (int k = 0; k < 16; k++) s += h4[((size_t)b * 16 + k) * 512 + c];
    z[i] = s * (1.f / 16.f);
  }
  __syncthreads();
  for (int i = t; i < 16 * 256; i += 512) {
    int b = i >> 8, d = i & 255;
    float a = bc1[d];
    for (int c = 0; c < 512; c++) a += z[(b << 9) + c] * Wc1[c * 256 + d];
    z1[i] = a;
  }
  __syncthreads();
  if (t < 256) {
    float s = 0.f, q = 0.f;
    for (int b = 0; b < 16; b++) { float a = z1[(b << 8) + t]; s += a; q += a * a; }
    float mean = s * (1.f / 16.f);
    float var = fmaxf(q * (1.f / 16.f) - mean * mean, 0.f);
    float scl = gc1[t] * rsqrtf(var + BN_EPS);
    sc[t] = scl; sh[t] = hc1[t] - mean * scl;
  }
  __syncthreads();
  for (int i = t; i < 16 * 256; i += 512) {
    int d = i & 255;
    z1[i] = fmaxf(z1[i] * sc[d] + sh[d], 0.f);
  }
  __syncthreads();
  for (int i = t; i < 16 * 128; i += 512) {
    int b = i >> 7, d = i & 127;
    float a = bc2[d];
    for (int c = 0; c < 256; c++) a += z1[(b << 8) + c] * Wc2[c * 128 + d];
    z2[i] = a;
  }
  __syncthreads();
  if (t < 128) {
    float s = 0.f, q = 0.f;
    for (int b = 0; b < 16; b++) { float a = z2[(b << 7) + t]; s += a; q += a * a; }
    float mean = s * (1.f / 16.f);
    float var = fmaxf(q * (1.f / 16.f) - mean * mean, 0.f);
    float scl = gc2[t] * rsqrtf(var + BN_EPS);
    sc[t] = scl; sh[t] = hc2[t] - mean * scl;
  }
  __syncthreads();
  for (int i = t; i < 16 * 128; i += 512) {
    int d = i & 127;
    z2[i] = fmaxf(z2[i] * sc[d] + sh[d], 0.f);
  }
  __syncthreads();
  for (int i = t; i < 640; i += 512) {
    int b = i / 40, d = i % 40;
    float a = bc3[d];
    for (int c = 0; c < 128; c++) a += z2[(b << 7) + c] * Wc3[c * 40 + d];
    out[i] = a;
  }
}

extern "C" void kernel_launch(void* const* d_in, const int* in_sizes, int n_in,
                              void* d_out, int out_size, void* d_ws, size_t ws_size,
                              hipStream_t stream) {
  (void)in_sizes; (void)n_in; (void)out_size; (void)ws_size;
  const float* x   = (const float*)d_in[0];
  const float* W1  = (const float*)d_in[1];
  const float* g1  = (const float*)d_in[2];
  const float* b1  = (const float*)d_in[3];
  const float* W2  = (const float*)d_in[4];
  const float* g2  = (const float*)d_in[5];
  const float* b2  = (const float*)d_in[6];
  const float* W3  = (const float*)d_in[7];
  const float* g3  = (const float*)d_in[8];
  const float* b3  = (const float*)d_in[9];
  const float* W4  = (const float*)d_in[10];
  const float* g4  = (const float*)d_in[11];
  const float* b4  = (const float*)d_in[12];
  const float* W5  = (const float*)d_in[13];
  const float* g5  = (const float*)d_in[14];
  const float* b5  = (const float*)d_in[15];
  const float* Wc1 = (const float*)d_in[16];
  const float* bc1 = (const float*)d_in[17];
  const float* gc1 = (const float*)d_in[18];
  const float* hc1 = (const float*)d_in[19];
  const float* Wc2 = (const float*)d_in[20];
  const float* bc2 = (const float*)d_in[21];
  const float* gc2 = (const float*)d_in[22];
  const float* hc2 = (const float*)d_in[23];
  const float* Wc3 = (const float*)d_in[24];
  const float* bc3 = (const float*)d_in[25];
  float* out = (float*)d_out;

  float* ws = (float*)d_ws;
  float* HA   = ws;                  // 2,097,152 (h1; stage2 out; stage4 out)
  float* HB   = HA + 2097152;        // 1,048,576 (stage1 out; stage3 out)
  float* YMIN = HB + 1048576;        // 1,048,576
  float* NP1  = YMIN + 1048576;      // 49,152
  float* NP2  = NP1 + 49152;         // 12,288
  float* NP3  = NP2 + 12288;         // 3,072
  float* NP4  = NP3 + 3072;          // 768
  int*   NIDX = (int*)(NP4 + 768);   // 262,144 ints
  float* PART = (float*)(NIDX + 262144);  // 5 * 65,536
  float* SS   = PART + 5 * 65536;         // 5 * 1,024

  hipMemsetAsync(PART, 0, 5 * 65536 * sizeof(float), stream);

  // --- MLP1 + BN(axes 0,1) + ReLU ---
  mlp1_kernel<<<(65536 * 32) / 256, 256, 0, stream>>>(x, W1, HA, 65536);
  stats_kernel<<<256, 256, 2 * 32 * sizeof(float), stream>>>(HA, 65536 * 32, 32, PART);
  finalize_kernel<<<1, 32, 0, stream>>>(PART, g1, b1, 65536.f, 32, SS);
  bn_apply_kernel<<<512, 256, 0, stream>>>(HA, HA, SS, 32, 65536 * 32);

  // --- stage 1: N=4096 -> M=1024, Ch=32 -> D=64 ---
  fps4_kernel<8, 8><<<16, 512, 0, stream>>>(x, NP1);
  knn_kernel<<<(16384 + 3) / 4, 256, 0, stream>>>(x, NP1, 4096, 1024, 16384, NIDX);
  gemm_kernel<<<512, 256, (4 * 16 * 36 + 2 * 64) * sizeof(float), stream>>>(
      x, HA, NP1, NIDX, W2, HB, YMIN, PART + 65536, 4096, 1024, 16384, 32, 36, 64, 8);
  finalize_kernel<<<1, 64, 0, stream>>>(PART + 65536, g2, b2, (float)(16384 * 16), 64, SS + 1024);
  bn_apply_kernel<<<512, 256, 0, stream>>>(HB, YMIN, SS + 1024, 64, 16384 * 64);

  // --- stage 2: N=1024 -> M=256, Ch=64 -> D=128 ---
  fps4_kernel<16, 1><<<16, 64, 0, stream>>>(NP1, NP2);
  knn_kernel<<<(4096 + 3) / 4, 256, 0, stream>>>(NP1, NP2, 1024, 256, 4096, NIDX);
  gemm_kernel<<<512, 256, (2 * 16 * 68 + 2 * 128) * sizeof(float), stream>>>(
      NP1, HB, NP2, NIDX, W3, HA, YMIN, PART + 2 * 65536, 1024, 256, 4096, 64, 68, 128, 4);
  finalize_kernel<<<1, 128, 0, stream>>>(PART + 2 * 65536, g3, b3, (float)(4096 * 16), 128, SS + 2048);
  bn_apply_kernel<<<512, 256, 0, stream>>>(HA, YMIN, SS + 2048, 128, 4096 * 128);

  // --- stage 3: N=256 -> M=64, Ch=128 -> D=256 ---
  fps4_kernel<4, 1><<<16, 64, 0, stream>>>(NP2, NP3);
  knn_kernel<<<(1024 + 3) / 4, 256, 0, stream>>>(NP2, NP3, 256, 64, 1024, NIDX);
  gemm_kernel<<<512, 256, (16 * 132 + 2 * 256) * sizeof(float), stream>>>(
      NP2, HA, NP3, NIDX, W4, HB, YMIN, PART + 3 * 65536, 256, 64, 1024, 128, 132, 256, 2);
  finalize_kernel<<<1, 256, 0, stream>>>(PART + 3 * 65536, g4, b4, (float)(1024 * 16), 256, SS + 3072);
  bn_apply_kernel<<<512, 256, 0, stream>>>(HB, YMIN, SS + 3072, 256, 1024 * 256);

  // --- stage 4: N=64 -> M=16, Ch=256 -> D=512 ---
  fps4_kernel<1, 1><<<16, 64, 0, stream>>>(NP3, NP4);
  knn_kernel<<<(256 + 3) / 4, 256, 0, stream>>>(NP3, NP4, 64, 16, 256, NIDX);
  gemm_kernel<<<256, 256, (16 * 260 + 2 * 512) * sizeof(float), stream>>>(
      NP3, HB, NP4, NIDX, W5, HA, YMIN, PART + 4 * 65536, 64, 16, 256, 256, 260, 512, 1);
  finalize_kernel<<<1, 512, 0, stream>>>(PART + 4 * 65536, g5, b5, (float)(256 * 16), 512, SS + 4096);
  bn_apply_kernel<<<512, 256, 0, stream>>>(HA, YMIN, SS + 4096, 512, 256 * 512);

  // --- classifier head ---
  classifier_kernel<<<1, 512, 0, stream>>>(HA, Wc1, bc1, gc1, hc1, Wc2, bc2, gc2, hc2, Wc3, bc3, out);
}